// Round 11
// baseline (222.276 us; speedup 1.0000x reference)
//
#include <hip/hip_runtime.h>

// Navier-Stokes physics-informed loss (f32 in, scalar f32 out).
// x,y: (64,3,512,512). Interior: b in [1,62], i,j in [1,510].
// r0 = |dudx + dvdy| ; r1 = |dudt + u*dudx + v*dudy + dpdx - MU*lap u| ;
// r2 = |dvdt + u*dvdx + v*dvdy + dpdy - MU*lap v|
// dudt = (u[b+1]-u[b-1])*32 ; d/dx,d/dy central *127.5 ; MU/DX^2 = 0.65025
//
// R4/R7/R9/R10: four structures, wall pinned 142-145us. Time independent of
// requested bytes, HBM fetch, DS ops, VGPR, barriers. VALUBusy ~22%.
// Hypothesis: per-iteration load-latency exposure x niters, with MLP capped
// by regalloc. R11: b-unroll x2 -> 56 independent float4 loads batched per
// iteration (planes b and b+1), halving latency-exposure points (31 -> 16)
// at identical bytes. VGPR allowed to float; grid 510 = 255 i-pairs x 2
// b-chunks stays single-round even at 2 blocks/CU.

constexpr int Wd   = 512;
constexpr int CSTR = 512 * 512;
constexpr int BSTR = 3 * 512 * 512;

__device__ __forceinline__ float4 ld4(const float* p) {
    return *reinterpret_cast<const float4*>(p);
}
__device__ __forceinline__ float4 ld4u(const float* p) {   // align-4 ok
    float4 v;
    __builtin_memcpy(&v, p, 16);
    return v;
}
__device__ __forceinline__ float4 scale4(float4 a, float s) {
    return make_float4(a.x * s, a.y * s, a.z * s, a.w * s);
}

// 12 spatial neighbor loads for one tensor at one plane (raw values).
struct Sp {
    float4 uxp, uxm, uyp, uym, vxp, vxm, vyp, vym, pxp, pxm, pyp, pym;
};
__device__ __forceinline__ Sp ldsp(const float* __restrict__ T, int c) {
    Sp r;
    r.uxp = ld4 (T + c + Wd);
    r.uxm = ld4 (T + c - Wd);
    r.uyp = ld4u(T + c + 1);
    r.uym = ld4u(T + c - 1);
    r.vxp = ld4 (T + c + CSTR + Wd);
    r.vxm = ld4 (T + c + CSTR - Wd);
    r.vyp = ld4u(T + c + CSTR + 1);
    r.vym = ld4u(T + c + CSTR - 1);
    r.pxp = ld4 (T + c + 2 * CSTR + Wd);
    r.pxm = ld4 (T + c + 2 * CSTR - Wd);
    r.pyp = ld4u(T + c + 2 * CSTR + 1);
    r.pym = ld4u(T + c + 2 * CSTR - 1);
    return r;
}

// Residuals for one plane: umS,ucS,vmS,vcS scaled centers (b-1,b);
// unR,vnR raw b+1 loads; g raw spatial loads at plane b.
__device__ __forceinline__ void resid(
    const Sp& g, float4 umS, float4 ucS, float4 unR,
    float4 vmS, float4 vcS, float4 vnR,
    float s, float sdx, float slap,
    float r0[4], float r1[4], float r2[4])
{
    const float ucA[4] = {ucS.x, ucS.y, ucS.z, ucS.w};
    const float vcA[4] = {vcS.x, vcS.y, vcS.z, vcS.w};
    const float umA[4] = {umS.x, umS.y, umS.z, umS.w};
    const float vmA[4] = {vmS.x, vmS.y, vmS.z, vmS.w};
    const float unA[4] = {unR.x, unR.y, unR.z, unR.w};
    const float vnA[4] = {vnR.x, vnR.y, vnR.z, vnR.w};
    const float uxpA[4] = {g.uxp.x, g.uxp.y, g.uxp.z, g.uxp.w};
    const float uxmA[4] = {g.uxm.x, g.uxm.y, g.uxm.z, g.uxm.w};
    const float uypA[4] = {g.uyp.x, g.uyp.y, g.uyp.z, g.uyp.w};
    const float uymA[4] = {g.uym.x, g.uym.y, g.uym.z, g.uym.w};
    const float vxpA[4] = {g.vxp.x, g.vxp.y, g.vxp.z, g.vxp.w};
    const float vxmA[4] = {g.vxm.x, g.vxm.y, g.vxm.z, g.vxm.w};
    const float vypA[4] = {g.vyp.x, g.vyp.y, g.vyp.z, g.vyp.w};
    const float vymA[4] = {g.vym.x, g.vym.y, g.vym.z, g.vym.w};
    const float pxpA[4] = {g.pxp.x, g.pxp.y, g.pxp.z, g.pxp.w};
    const float pxmA[4] = {g.pxm.x, g.pxm.y, g.pxm.z, g.pxm.w};
    const float pypA[4] = {g.pyp.x, g.pyp.y, g.pyp.z, g.pyp.w};
    const float pymA[4] = {g.pym.x, g.pym.y, g.pym.z, g.pym.w};

    #pragma unroll
    for (int k = 0; k < 4; ++k) {
        const float dudx = (uxpA[k] - uxmA[k]) * sdx;
        const float dudy = (uypA[k] - uymA[k]) * sdx;
        const float dvdx = (vxpA[k] - vxmA[k]) * sdx;
        const float dvdy = (vypA[k] - vymA[k]) * sdx;
        const float dpdx = (pxpA[k] - pxmA[k]) * sdx;
        const float dpdy = (pypA[k] - pymA[k]) * sdx;
        const float lapu = (uxpA[k] + uxmA[k] + uypA[k] + uymA[k]) * slap
                         - 2.601f * ucA[k];
        const float lapv = (vxpA[k] + vxmA[k] + vypA[k] + vymA[k]) * slap
                         - 2.601f * vcA[k];
        r0[k] = fabsf(dudx + dvdy);
        r1[k] = fabsf((unA[k] * s - umA[k]) * 32.0f
                      + ucA[k] * dudx + vcA[k] * dudy + dpdx - lapu);
        r2[k] = fabsf((vnA[k] * s - vmA[k]) * 32.0f
                      + ucA[k] * dvdx + vcA[k] * dvdy + dpdy - lapv);
    }
}

__global__ __launch_bounds__(256)
void ns_loss_kernel(const float* __restrict__ X, const float* __restrict__ Y,
                    const float* __restrict__ stdp, double* __restrict__ acc)
{
    const float s    = *stdp;
    const float sdx  = s * 127.5f;
    const float slap = s * 0.65025f;

    // m204 bijective XCD swizzle: nwg = 510, q = 63, r = 6.
    const int orig = blockIdx.x;
    const int q = 63, r = 6;
    const int xcd  = orig & 7;
    const int wg   = (xcd < r ? xcd * (q + 1) : r * (q + 1) + (xcd - r) * q)
                   + (orig >> 3);
    const int z = wg / 255;              // b-chunk 0..1
    const int y = wg % 255;              // i-pair 0..254

    const int tid = threadIdx.x;
    const int jt  = tid & 127;
    const int io  = tid >> 7;
    const int i   = 1 + 2 * y + io;      // 1..510
    const int j0  = jt << 2;             // 0..508
    const int bs  = 1 + 31 * z;          // 1 or 32, 31 planes each

    int c = bs * BSTR + i * Wd + j0;

    float4 xum = scale4(ld4(X + c - BSTR), s);
    float4 xuc = scale4(ld4(X + c), s);
    float4 xvm = scale4(ld4(X + c - BSTR + CSTR), s);
    float4 xvc = scale4(ld4(X + c + CSTR), s);
    float4 yum = scale4(ld4(Y + c - BSTR), s);
    float4 yuc = scale4(ld4(Y + c), s);
    float4 yvm = scale4(ld4(Y + c - BSTR + CSTR), s);
    float4 yvc = scale4(ld4(Y + c + CSTR), s);

    const float w[4] = {(j0 != 0) ? 1.0f : 0.0f, 1.0f, 1.0f,
                        (j0 != 508) ? 1.0f : 0.0f};

    float s0 = 0.0f, s1 = 0.0f, s2 = 0.0f;

    // 15 double-steps (planes b, b+1) + 1 tail plane = 31 planes.
    for (int it = 0; it + 1 < 31; it += 2) {
        // ---- batched loads: 28 per tensor, all independent ----
        const float4 xu1 = ld4(X + c + BSTR);
        const float4 xu2 = ld4(X + c + 2 * BSTR);
        const float4 xv1 = ld4(X + c + BSTR + CSTR);
        const float4 xv2 = ld4(X + c + 2 * BSTR + CSTR);
        const Sp xg0 = ldsp(X, c);
        const Sp xg1 = ldsp(X, c + BSTR);
        const float4 yu1 = ld4(Y + c + BSTR);
        const float4 yu2 = ld4(Y + c + 2 * BSTR);
        const float4 yv1 = ld4(Y + c + BSTR + CSTR);
        const float4 yv2 = ld4(Y + c + 2 * BSTR + CSTR);
        const Sp yg0 = ldsp(Y, c);
        const Sp yg1 = ldsp(Y, c + BSTR);

        // ---- X residuals, planes b and b+1 ----
        float r0x0[4], r1x0[4], r2x0[4], r0x1[4], r1x1[4], r2x1[4];
        resid(xg0, xum, xuc, xu1, xvm, xvc, xv1, s, sdx, slap,
              r0x0, r1x0, r2x0);
        const float4 xu1s = scale4(xu1, s), xv1s = scale4(xv1, s);
        resid(xg1, xuc, xu1s, xu2, xvc, xv1s, xv2, s, sdx, slap,
              r0x1, r1x1, r2x1);
        xum = xu1s; xuc = scale4(xu2, s);
        xvm = xv1s; xvc = scale4(xv2, s);

        // ---- Y residuals ----
        float r0y0[4], r1y0[4], r2y0[4], r0y1[4], r1y1[4], r2y1[4];
        resid(yg0, yum, yuc, yu1, yvm, yvc, yv1, s, sdx, slap,
              r0y0, r1y0, r2y0);
        const float4 yu1s = scale4(yu1, s), yv1s = scale4(yv1, s);
        resid(yg1, yuc, yu1s, yu2, yvc, yv1s, yv2, s, sdx, slap,
              r0y1, r1y1, r2y1);
        yum = yu1s; yuc = scale4(yu2, s);
        yvm = yv1s; yvc = scale4(yv2, s);

        // ---- accumulate both planes ----
        #pragma unroll
        for (int k = 0; k < 4; ++k) {
            const float a0 = (r0y0[k] - r0x0[k]) * w[k];
            const float a1 = (r1y0[k] - r1x0[k]) * w[k];
            const float a2 = (r2y0[k] - r2x0[k]) * w[k];
            const float b0 = (r0y1[k] - r0x1[k]) * w[k];
            const float b1 = (r1y1[k] - r1x1[k]) * w[k];
            const float b2 = (r2y1[k] - r2x1[k]) * w[k];
            s0 += a0 * a0 + b0 * b0;
            s1 += a1 * a1 + b1 * b1;
            s2 += a2 * a2 + b2 * b2;
        }
        c += 2 * BSTR;
    }

    // ---- tail plane (it = 30) ----
    {
        const float4 xu1 = ld4(X + c + BSTR);
        const float4 xv1 = ld4(X + c + BSTR + CSTR);
        const Sp xg0 = ldsp(X, c);
        const float4 yu1 = ld4(Y + c + BSTR);
        const float4 yv1 = ld4(Y + c + BSTR + CSTR);
        const Sp yg0 = ldsp(Y, c);

        float r0x0[4], r1x0[4], r2x0[4], r0y0[4], r1y0[4], r2y0[4];
        resid(xg0, xum, xuc, xu1, xvm, xvc, xv1, s, sdx, slap,
              r0x0, r1x0, r2x0);
        resid(yg0, yum, yuc, yu1, yvm, yvc, yv1, s, sdx, slap,
              r0y0, r1y0, r2y0);

        #pragma unroll
        for (int k = 0; k < 4; ++k) {
            const float a0 = (r0y0[k] - r0x0[k]) * w[k];
            const float a1 = (r1y0[k] - r1x0[k]) * w[k];
            const float a2 = (r2y0[k] - r2x0[k]) * w[k];
            s0 += a0 * a0;
            s1 += a1 * a1;
            s2 += a2 * a2;
        }
    }

    // ---- reduction: f32 wave shuffle -> LDS -> f64 atomic ----
    for (int o = 32; o > 0; o >>= 1) {
        s0 += __shfl_down(s0, o);
        s1 += __shfl_down(s1, o);
        s2 += __shfl_down(s2, o);
    }
    __shared__ float sm[3][4];
    const int wid = threadIdx.x >> 6, lane = threadIdx.x & 63;
    if (lane == 0) { sm[0][wid] = s0; sm[1][wid] = s1; sm[2][wid] = s2; }
    __syncthreads();
    if (threadIdx.x == 0) {
        atomicAdd(&acc[0], (double)sm[0][0] + (double)sm[0][1]
                         + (double)sm[0][2] + (double)sm[0][3]);
        atomicAdd(&acc[1], (double)sm[1][0] + (double)sm[1][1]
                         + (double)sm[1][2] + (double)sm[1][3]);
        atomicAdd(&acc[2], (double)sm[2][0] + (double)sm[2][1]
                         + (double)sm[2][2] + (double)sm[2][3]);
    }
}

__global__ void ns_finalize_kernel(const double* __restrict__ acc,
                                   float* __restrict__ out)
{
    if (threadIdx.x == 0) {
        const double N = 62.0 * 510.0 * 510.0;
        out[0] = (float)(1.0e-3 * (acc[0] + acc[1] + acc[2]) / N);
    }
}

extern "C" void kernel_launch(void* const* d_in, const int* in_sizes, int n_in,
                              void* d_out, int out_size, void* d_ws, size_t ws_size,
                              hipStream_t stream) {
    const float* X    = (const float*)d_in[0];
    const float* Y    = (const float*)d_in[1];
    const float* stdp = (const float*)d_in[2];
    float* out  = (float*)d_out;
    double* acc = (double*)d_ws;

    hipMemsetAsync(acc, 0, 3 * sizeof(double), stream);

    dim3 block(256);
    dim3 grid(510);   // 255 i-pairs x 2 b-chunks; single-round even at 2/CU
    ns_loss_kernel<<<grid, block, 0, stream>>>(X, Y, stdp, acc);
    ns_finalize_kernel<<<1, 64, 0, stream>>>(acc, out);
}

// Round 12
// 141.818 us; speedup vs baseline: 1.5673x; 1.5673x over previous
//
#include <hip/hip_runtime.h>

// Navier-Stokes physics-informed loss (f32 in, scalar f32 out).
// x,y: (64,3,512,512). Interior: b in [1,62], i,j in [1,510].
// r0 = |dudx + dvdy| ; r1 = |dudt + u*dudx + v*dudy + dpdx - MU*lap u| ;
// r2 = |dvdt + u*dvdx + v*dvdy + dpdy - MU*lap v|
// dudt = (u[b+1]-u[b-1])*32 ; central *127.5 ; MU/DX^2 = 0.65025
//
// R4-R11: wall pinned 142-145us across four structures; time independent of
// requested/HBM bytes, DS ops, VGPR(36-88). Common property: loads issued
// and consumed within the same iteration -> latency exposed every iter.
// R12: SOFTWARE PIPELINE at tensor granularity. Ping-pong bufA/bufB:
//   phase A: issue Y(p) -> bufB ; compute X(p) from bufA   [14 loads in flight]
//   phase B: issue X(p+1) -> bufA ; compute Y(p) from bufB ; accumulate
// No barriers anywhere -> compiler can emit counted vmcnt(14) (m97-style).
// Static buffer naming (rule #20), no dynamic indexing. Grid 510 = 255
// i-pairs x 2 b-chunks: single round whether capacity is 2 or 3 blocks/CU.

constexpr int Wd   = 512;
constexpr int CSTR = 512 * 512;
constexpr int BSTR = 3 * 512 * 512;

__device__ __forceinline__ float4 ld4(const float* p) {
    return *reinterpret_cast<const float4*>(p);
}
__device__ __forceinline__ float4 ld4u(const float* p) {   // align-4 ok
    float4 v;
    __builtin_memcpy(&v, p, 16);
    return v;
}
__device__ __forceinline__ float4 scale4(float4 a, float s) {
    return make_float4(a.x * s, a.y * s, a.z * s, a.w * s);
}

// One plane's loads for one tensor: 14 independent float4.
struct Buf {
    float4 un, vn;                          // u,v at b+1 (center col)
    float4 uxp, uxm, uyp, uym;              // u neighbors
    float4 vxp, vxm, vyp, vym;              // v neighbors
    float4 pxp, pxm, pyp, pym;              // p neighbors
};

__device__ __forceinline__ void issue(const float* __restrict__ T, int c,
                                      Buf& b) {
    b.un  = ld4 (T + c + BSTR);
    b.vn  = ld4 (T + c + BSTR + CSTR);
    b.uxp = ld4 (T + c + Wd);
    b.uxm = ld4 (T + c - Wd);
    b.uyp = ld4u(T + c + 1);
    b.uym = ld4u(T + c - 1);
    b.vxp = ld4 (T + c + CSTR + Wd);
    b.vxm = ld4 (T + c + CSTR - Wd);
    b.vyp = ld4u(T + c + CSTR + 1);
    b.vym = ld4u(T + c + CSTR - 1);
    b.pxp = ld4 (T + c + 2 * CSTR + Wd);
    b.pxm = ld4 (T + c + 2 * CSTR - Wd);
    b.pyp = ld4u(T + c + 2 * CSTR + 1);
    b.pym = ld4u(T + c + 2 * CSTR - 1);
}

// Residuals for one tensor at one plane; advances carried scaled centers.
__device__ __forceinline__ void compute(
    const Buf& g, float s, float sdx, float slap,
    float4& um, float4& uc, float4& vm, float4& vc,
    float r0[4], float r1[4], float r2[4])
{
    const float ucA[4] = {uc.x, uc.y, uc.z, uc.w};
    const float vcA[4] = {vc.x, vc.y, vc.z, vc.w};
    const float umA[4] = {um.x, um.y, um.z, um.w};
    const float vmA[4] = {vm.x, vm.y, vm.z, vm.w};
    const float unA[4] = {g.un.x, g.un.y, g.un.z, g.un.w};
    const float vnA[4] = {g.vn.x, g.vn.y, g.vn.z, g.vn.w};
    const float uxpA[4] = {g.uxp.x, g.uxp.y, g.uxp.z, g.uxp.w};
    const float uxmA[4] = {g.uxm.x, g.uxm.y, g.uxm.z, g.uxm.w};
    const float uypA[4] = {g.uyp.x, g.uyp.y, g.uyp.z, g.uyp.w};
    const float uymA[4] = {g.uym.x, g.uym.y, g.uym.z, g.uym.w};
    const float vxpA[4] = {g.vxp.x, g.vxp.y, g.vxp.z, g.vxp.w};
    const float vxmA[4] = {g.vxm.x, g.vxm.y, g.vxm.z, g.vxm.w};
    const float vypA[4] = {g.vyp.x, g.vyp.y, g.vyp.z, g.vyp.w};
    const float vymA[4] = {g.vym.x, g.vym.y, g.vym.z, g.vym.w};
    const float pxpA[4] = {g.pxp.x, g.pxp.y, g.pxp.z, g.pxp.w};
    const float pxmA[4] = {g.pxm.x, g.pxm.y, g.pxm.z, g.pxm.w};
    const float pypA[4] = {g.pyp.x, g.pyp.y, g.pyp.z, g.pyp.w};
    const float pymA[4] = {g.pym.x, g.pym.y, g.pym.z, g.pym.w};

    #pragma unroll
    for (int k = 0; k < 4; ++k) {
        const float dudx = (uxpA[k] - uxmA[k]) * sdx;
        const float dudy = (uypA[k] - uymA[k]) * sdx;
        const float dvdx = (vxpA[k] - vxmA[k]) * sdx;
        const float dvdy = (vypA[k] - vymA[k]) * sdx;
        const float dpdx = (pxpA[k] - pxmA[k]) * sdx;
        const float dpdy = (pypA[k] - pymA[k]) * sdx;
        const float lapu = (uxpA[k] + uxmA[k] + uypA[k] + uymA[k]) * slap
                         - 2.601f * ucA[k];
        const float lapv = (vxpA[k] + vxmA[k] + vypA[k] + vymA[k]) * slap
                         - 2.601f * vcA[k];
        r0[k] = fabsf(dudx + dvdy);
        r1[k] = fabsf((unA[k] * s - umA[k]) * 32.0f
                      + ucA[k] * dudx + vcA[k] * dudy + dpdx - lapu);
        r2[k] = fabsf((vnA[k] * s - vmA[k]) * 32.0f
                      + ucA[k] * dvdx + vcA[k] * dvdy + dpdy - lapv);
    }

    um = uc; uc = scale4(g.un, s);
    vm = vc; vc = scale4(g.vn, s);
}

__global__ __launch_bounds__(256)
void ns_loss_kernel(const float* __restrict__ X, const float* __restrict__ Y,
                    const float* __restrict__ stdp, double* __restrict__ acc)
{
    const float s    = *stdp;
    const float sdx  = s * 127.5f;
    const float slap = s * 0.65025f;

    // m204 bijective XCD swizzle: nwg = 510, q = 63, r = 6.
    const int orig = blockIdx.x;
    const int q = 63, r = 6;
    const int xcd  = orig & 7;
    const int wg   = (xcd < r ? xcd * (q + 1) : r * (q + 1) + (xcd - r) * q)
                   + (orig >> 3);
    const int z = wg / 255;              // b-chunk 0..1
    const int y = wg % 255;              // i-pair 0..254

    const int tid = threadIdx.x;
    const int jt  = tid & 127;
    const int io  = tid >> 7;
    const int i   = 1 + 2 * y + io;      // 1..510
    const int j0  = jt << 2;             // 0..508
    const int bs  = 1 + 31 * z;          // 31 planes per chunk
    const int n   = 31;

    int c = bs * BSTR + i * Wd + j0;

    float4 xum = scale4(ld4(X + c - BSTR), s);
    float4 xuc = scale4(ld4(X + c), s);
    float4 xvm = scale4(ld4(X + c - BSTR + CSTR), s);
    float4 xvc = scale4(ld4(X + c + CSTR), s);
    float4 yum = scale4(ld4(Y + c - BSTR), s);
    float4 yuc = scale4(ld4(Y + c), s);
    float4 yvm = scale4(ld4(Y + c - BSTR + CSTR), s);
    float4 yvc = scale4(ld4(Y + c + CSTR), s);

    const float w[4] = {(j0 != 0) ? 1.0f : 0.0f, 1.0f, 1.0f,
                        (j0 != 508) ? 1.0f : 0.0f};

    float s0 = 0.0f, s1 = 0.0f, s2 = 0.0f;

    Buf bufA, bufB;
    issue(X, c, bufA);                   // prologue: X plane 0 in flight

    for (int p = 0; p < n; ++p) {
        // clamp next-plane address on the last iteration (values unused)
        const int cnext = c + ((p + 1 < n) ? BSTR : 0);

        // ---- phase A: launch Y(p), compute X(p) ----
        issue(Y, c, bufB);
        float r0x[4], r1x[4], r2x[4];
        compute(bufA, s, sdx, slap, xum, xuc, xvm, xvc, r0x, r1x, r2x);

        // ---- phase B: launch X(p+1), compute Y(p), accumulate ----
        issue(X, cnext, bufA);
        float r0y[4], r1y[4], r2y[4];
        compute(bufB, s, sdx, slap, yum, yuc, yvm, yvc, r0y, r1y, r2y);

        #pragma unroll
        for (int k = 0; k < 4; ++k) {
            const float e0 = (r0y[k] - r0x[k]) * w[k];
            const float e1 = (r1y[k] - r1x[k]) * w[k];
            const float e2 = (r2y[k] - r2x[k]) * w[k];
            s0 += e0 * e0;
            s1 += e1 * e1;
            s2 += e2 * e2;
        }
        c = cnext;
    }

    // ---- reduction: f32 wave shuffle -> LDS -> f64 atomic ----
    for (int o = 32; o > 0; o >>= 1) {
        s0 += __shfl_down(s0, o);
        s1 += __shfl_down(s1, o);
        s2 += __shfl_down(s2, o);
    }
    __shared__ float sm[3][4];
    const int wid = threadIdx.x >> 6, lane = threadIdx.x & 63;
    if (lane == 0) { sm[0][wid] = s0; sm[1][wid] = s1; sm[2][wid] = s2; }
    __syncthreads();
    if (threadIdx.x == 0) {
        atomicAdd(&acc[0], (double)sm[0][0] + (double)sm[0][1]
                         + (double)sm[0][2] + (double)sm[0][3]);
        atomicAdd(&acc[1], (double)sm[1][0] + (double)sm[1][1]
                         + (double)sm[1][2] + (double)sm[1][3]);
        atomicAdd(&acc[2], (double)sm[2][0] + (double)sm[2][1]
                         + (double)sm[2][2] + (double)sm[2][3]);
    }
}

__global__ void ns_finalize_kernel(const double* __restrict__ acc,
                                   float* __restrict__ out)
{
    if (threadIdx.x == 0) {
        const double N = 62.0 * 510.0 * 510.0;
        out[0] = (float)(1.0e-3 * (acc[0] + acc[1] + acc[2]) / N);
    }
}

extern "C" void kernel_launch(void* const* d_in, const int* in_sizes, int n_in,
                              void* d_out, int out_size, void* d_ws, size_t ws_size,
                              hipStream_t stream) {
    const float* X    = (const float*)d_in[0];
    const float* Y    = (const float*)d_in[1];
    const float* stdp = (const float*)d_in[2];
    float* out  = (float*)d_out;
    double* acc = (double*)d_ws;

    hipMemsetAsync(acc, 0, 3 * sizeof(double), stream);

    dim3 block(256);
    dim3 grid(510);   // 255 i-pairs x 2 b-chunks; single-round at 2-3 blk/CU
    ns_loss_kernel<<<grid, block, 0, stream>>>(X, Y, stdp, acc);
    ns_finalize_kernel<<<1, 64, 0, stream>>>(acc, out);
}